// Round 6
// baseline (48.844 us; speedup 1.0000x reference)
//
#include <hip/hip_runtime.h>

#define SL1_BETA 0.01f
#define NSLOT   256            // one 128B line per slot (padded)
#define WCHUNK  64             // samples per wave-chunk
#define WBUF    3584           // per-wave LDS bytes: 1024(tq)+1024(qe)+768(tt)+768(te)
#define NW      4              // waves per block
#define LDS_BYTES (NW * WBUF)  // 14336 -> 8 blocks/CU -> 32 waves/CU

#define AS1(p) ((const __attribute__((address_space(1))) void*)(p))
#define AS3(p) ((__attribute__((address_space(3))) void*)(p))

__device__ __forceinline__ float smooth_l1(float x) {
    float d = fabsf(x);
    return (d < SL1_BETA) ? (0.5f * d * d / SL1_BETA) : (d - 0.5f * SL1_BETA);
}

__device__ __forceinline__ void quat_to_mat9(float4 q, float R[9]) {
    float r = q.x, i = q.y, j = q.z, k = q.w;
    float two_s = 2.0f / (r*r + i*i + j*j + k*k);
    R[0] = 1.0f - two_s * (j*j + k*k);
    R[1] = two_s * (i*j - k*r);
    R[2] = two_s * (i*k + j*r);
    R[3] = two_s * (i*j + k*r);
    R[4] = 1.0f - two_s * (i*i + k*k);
    R[5] = two_s * (j*k - i*r);
    R[6] = two_s * (i*k - j*r);
    R[7] = two_s * (j*k + i*r);
    R[8] = 1.0f - two_s * (i*i + j*j);
}

__device__ __forceinline__ void sample_loss(float4 q, float4 e,
                                            float t0, float t1, float t2,
                                            float p0, float p1, float p2,
                                            float& sr, float& st) {
    float R[9], P[9];
    quat_to_mat9(q, R);
    quat_to_mat9(e, P);

    // loss_r: sum smooth_l1(R^T P - I)
    #pragma unroll
    for (int i2 = 0; i2 < 3; ++i2) {
        #pragma unroll
        for (int j2 = 0; j2 < 3; ++j2) {
            float v = R[0*3 + i2] * P[0*3 + j2]
                    + R[1*3 + i2] * P[1*3 + j2]
                    + R[2*3 + i2] * P[2*3 + j2];
            sr += smooth_l1(v - (i2 == j2 ? 1.0f : 0.0f));
        }
    }

    // T_inv = -R^T t
    float Ti0 = -(R[0]*t0 + R[3]*t1 + R[6]*t2);
    float Ti1 = -(R[1]*t0 + R[4]*t1 + R[7]*t2);
    float Ti2 = -(R[2]*t0 + R[5]*t1 + R[8]*t2);

    st += smooth_l1(P[0]*Ti0 + P[1]*Ti1 + P[2]*Ti2 + p0);
    st += smooth_l1(P[3]*Ti0 + P[4]*Ti1 + P[5]*Ti2 + p1);
    st += smooth_l1(P[6]*Ti0 + P[7]*Ti1 + P[8]*Ti2 + p2);
}

// Persistent per-wave streaming: each wave owns a private 3.5 KB LDS chunk
// (WCHUNK=64 samples) and loops {issue 4 DMAs; vmcnt(0); compute}. No
// __syncthreads anywhere — waves are fully decoupled; latency is hidden by
// 32 waves/CU of TLP with independent phases.
__global__ __launch_bounds__(256, 8) void euler_loss_kernel(
        const float*  __restrict__ tt,   // target_transl (b,3)
        const float4* __restrict__ tq,   // target_rot    (b,4)
        const float*  __restrict__ te,   // transl_err    (b,3)
        const float4* __restrict__ qe,   // rot_err       (b,4)
        double* __restrict__ acc, int b) {
    __shared__ __align__(16) unsigned char smem[LDS_BYTES];
    const int t    = threadIdx.x;
    const int lane = t & 63;
    const int wid  = t >> 6;
    unsigned char* my = smem + (size_t)wid * WBUF;

    const int gw   = blockIdx.x * NW + wid;         // global wave id
    const int totW = gridDim.x * NW;
    const long long nch = ((long long)b + WCHUNK - 1) / WCHUNK;

    const float4* tqL = (const float4*)(my);
    const float4* qeL = (const float4*)(my + 1024);
    const float*  ttL = (const float*)(my + 2048);
    const float*  teL = (const float*)(my + 2816);

    float sr = 0.0f, st = 0.0f;
    for (long long c = gw; c < nch; c += totW) {
        long long s0 = c * WCHUNK;
        bool full = (s0 + WCHUNK <= (long long)b);   // wave-uniform
        if (full) {
            // previous iteration's ds_reads must be drained before overwrite
            asm volatile("s_waitcnt lgkmcnt(0)" ::: "memory");
            // 4 fire-and-forget DMAs (1 KB / 1 KB / 768 B / 768 B)
            __builtin_amdgcn_global_load_lds(
                AS1((const unsigned char*)tq + s0 * 16 + (size_t)lane * 16),
                AS3(my), 16, 0, 0);
            __builtin_amdgcn_global_load_lds(
                AS1((const unsigned char*)qe + s0 * 16 + (size_t)lane * 16),
                AS3(my + 1024), 16, 0, 0);
            if (lane < 48) {
                __builtin_amdgcn_global_load_lds(
                    AS1((const unsigned char*)tt + s0 * 12 + (size_t)lane * 16),
                    AS3(my + 2048), 16, 0, 0);
                __builtin_amdgcn_global_load_lds(
                    AS1((const unsigned char*)te + s0 * 12 + (size_t)lane * 16),
                    AS3(my + 2816), 16, 0, 0);
            }
            asm volatile("s_waitcnt vmcnt(0)" ::: "memory");

            float4 q = tqL[lane];
            float4 e = qeL[lane];
            sample_loss(q, e,
                        ttL[3*lane], ttL[3*lane+1], ttL[3*lane+2],
                        teL[3*lane], teL[3*lane+1], teL[3*lane+2], sr, st);
        } else {
            long long s = s0 + lane;
            if (s < (long long)b) {
                sample_loss(tq[s], qe[s],
                            tt[3*s], tt[3*s+1], tt[3*s+2],
                            te[3*s], te[3*s+1], te[3*s+2], sr, st);
            }
        }
    }

    // wave (64-lane) reduction, one atomic pair per wave
    #pragma unroll
    for (int off = 32; off > 0; off >>= 1) {
        sr += __shfl_down(sr, off);
        st += __shfl_down(st, off);
    }
    if (lane == 0) {
        int slot = gw & (NSLOT - 1);
        double* sp = (double*)((unsigned char*)acc + (size_t)slot * 128);
        atomicAdd(&sp[0], (double)sr);
        atomicAdd(&sp[1], (double)st);
    }
}

__global__ __launch_bounds__(256) void euler_loss_finalize(
        const double* __restrict__ acc, float* __restrict__ out, int b) {
    int t = threadIdx.x;                 // 256 threads, one slot each
    const double* sp = (const double*)((const unsigned char*)acc + (size_t)t * 128);
    double sr = sp[0], st = sp[1];
    #pragma unroll
    for (int off = 32; off > 0; off >>= 1) {
        sr += __shfl_down(sr, off);
        st += __shfl_down(st, off);
    }
    __shared__ double s_r[4], s_t[4];
    int lane = t & 63, wid = t >> 6;
    if (lane == 0) { s_r[wid] = sr; s_t[wid] = st; }
    __syncthreads();
    if (t == 0) {
        double tr  = s_r[0] + s_r[1] + s_r[2] + s_r[3];
        double tts = s_t[0] + s_t[1] + s_t[2] + s_t[3];
        double inv_b = 1.0 / (double)b;
        double lr = tr * inv_b;
        double lt = tts * inv_b;
        out[0] = (float)(lr + lt);
        out[1] = (float)lt;
        out[2] = (float)lr;
    }
}

extern "C" void kernel_launch(void* const* d_in, const int* in_sizes, int n_in,
                              void* d_out, int out_size, void* d_ws, size_t ws_size,
                              hipStream_t stream) {
    // input order: point_clouds(0, unused), target_transl(1), target_rot(2),
    //              transl_err(3), rot_err(4)
    const float*  tt = (const float*)d_in[1];
    const float4* tq = (const float4*)d_in[2];
    const float*  te = (const float*)d_in[3];
    const float4* qe = (const float4*)d_in[4];
    float* out = (float*)d_out;
    int b = in_sizes[1] / 3;             // 2097152

    double* acc = (double*)d_ws;
    hipMemsetAsync(acc, 0, (size_t)NSLOT * 128, stream);   // 32 KB of slots

    // 8 blocks/CU * 256 CU = 2048 persistent blocks (= 8192 waves; 4 chunks/wave)
    int grid = 2048;
    long long nch = ((long long)b + WCHUNK - 1) / WCHUNK;
    long long maxg = (nch + NW - 1) / NW;          // don't launch idle blocks
    if ((long long)grid > maxg) grid = (int)maxg;
    euler_loss_kernel<<<grid, 256, 0, stream>>>(tt, tq, te, qe, acc, b);
    euler_loss_finalize<<<1, 256, 0, stream>>>(acc, out, b);
}

// Round 7
// 35.407 us; speedup vs baseline: 1.3795x; 1.3795x over previous
//
#include <hip/hip_runtime.h>

#define SL1_BETA 0.01f
#define NSLOT 256              // one 128B line per slot (padded)
#define CHUNK 256              // samples per buffer
#define BUFB  14336            // per-buffer bytes: 4096(tq)+4096(qe)+3072(tt)+3072(te)
#define LDS_BYTES (2 * BUFB)   // 28672 -> 5 blocks/CU

#define AS1(p) ((const __attribute__((address_space(1))) void*)(p))
#define AS3(p) ((__attribute__((address_space(3))) void*)(p))

__device__ __forceinline__ float smooth_l1(float x) {
    float d = fabsf(x);
    return (d < SL1_BETA) ? (0.5f * d * d / SL1_BETA) : (d - 0.5f * SL1_BETA);
}

__device__ __forceinline__ void quat_to_mat9(float4 q, float R[9]) {
    float r = q.x, i = q.y, j = q.z, k = q.w;
    float two_s = 2.0f / (r*r + i*i + j*j + k*k);
    R[0] = 1.0f - two_s * (j*j + k*k);
    R[1] = two_s * (i*j - k*r);
    R[2] = two_s * (i*k + j*r);
    R[3] = two_s * (i*j + k*r);
    R[4] = 1.0f - two_s * (i*i + k*k);
    R[5] = two_s * (j*k - i*r);
    R[6] = two_s * (i*k - j*r);
    R[7] = two_s * (j*k + i*r);
    R[8] = 1.0f - two_s * (i*i + j*j);
}

__device__ __forceinline__ void sample_loss(float4 q, float4 e,
                                            float t0, float t1, float t2,
                                            float p0, float p1, float p2,
                                            float& sr, float& st) {
    float R[9], P[9];
    quat_to_mat9(q, R);
    quat_to_mat9(e, P);

    // loss_r: sum smooth_l1(R^T P - I)
    #pragma unroll
    for (int i2 = 0; i2 < 3; ++i2) {
        #pragma unroll
        for (int j2 = 0; j2 < 3; ++j2) {
            float v = R[0*3 + i2] * P[0*3 + j2]
                    + R[1*3 + i2] * P[1*3 + j2]
                    + R[2*3 + i2] * P[2*3 + j2];
            sr += smooth_l1(v - (i2 == j2 ? 1.0f : 0.0f));
        }
    }

    // T_inv = -R^T t
    float Ti0 = -(R[0]*t0 + R[3]*t1 + R[6]*t2);
    float Ti1 = -(R[1]*t0 + R[4]*t1 + R[7]*t2);
    float Ti2 = -(R[2]*t0 + R[5]*t1 + R[8]*t2);

    st += smooth_l1(P[0]*Ti0 + P[1]*Ti1 + P[2]*Ti2 + p0);
    st += smooth_l1(P[3]*Ti0 + P[4]*Ti1 + P[5]*Ti2 + p1);
    st += smooth_l1(P[6]*Ti0 + P[7]*Ti1 + P[8]*Ti2 + p2);
}

// Stage one CHUNK (14 x 1KB DMA ops) split across 4 waves: wave w issues
// ops {w, w+4, w+8, w+12(<14)} -> waves 0,1 issue 4 ops; waves 2,3 issue 3.
__device__ __forceinline__ void stage_ops(
        const unsigned char* tq8, const unsigned char* qe8,
        const unsigned char* tt8, const unsigned char* te8,
        unsigned char* bufbase, long long s0, int wid, int lane) {
    #pragma unroll
    for (int u = 0; u < 4; ++u) {
        int o = wid + 4 * u;
        if (o < 14) {                      // wave-uniform branch
            const unsigned char* src;
            if (o < 4)       src = tq8 + s0 * 16 + (size_t)o        * 1024;
            else if (o < 8)  src = qe8 + s0 * 16 + (size_t)(o - 4)  * 1024;
            else if (o < 11) src = tt8 + s0 * 12 + (size_t)(o - 8)  * 1024;
            else             src = te8 + s0 * 12 + (size_t)(o - 11) * 1024;
            __builtin_amdgcn_global_load_lds(AS1(src + (size_t)lane * 16),
                                             AS3(bufbase + (size_t)o * 1024),
                                             16, 0, 0);
        }
    }
}

// Persistent blocks, double-buffered LDS staging with COUNTED vmcnt:
// stage(next -> buf^1); vmcnt(k) keeps next's k DMAs in flight while
// guaranteeing buf's are complete; raw s_barrier (NOT __syncthreads —
// that would compiler-drain vmcnt(0) and kill the pipeline).
__global__ __launch_bounds__(256, 5) void euler_loss_kernel(
        const float*  __restrict__ tt,   // target_transl (b,3)
        const float4* __restrict__ tq,   // target_rot    (b,4)
        const float*  __restrict__ te,   // transl_err    (b,3)
        const float4* __restrict__ qe,   // rot_err       (b,4)
        double* __restrict__ acc, int b) {
    __shared__ __align__(16) unsigned char smem[LDS_BYTES];
    const int t    = threadIdx.x;
    const int lane = t & 63;
    const int wid  = t >> 6;

    const unsigned char* tq8 = (const unsigned char*)tq;
    const unsigned char* qe8 = (const unsigned char*)qe;
    const unsigned char* tt8 = (const unsigned char*)tt;
    const unsigned char* te8 = (const unsigned char*)te;

    float sr = 0.0f, st = 0.0f;

    long long nfull = (long long)b / CHUNK;
    long long c     = blockIdx.x;
    long long step  = gridDim.x;
    int cur = 0;
    bool have = (c < nfull);
    if (have) stage_ops(tq8, qe8, tt8, te8, smem, c * CHUNK, wid, lane);

    while (have) {
        long long cn = c + step;
        bool nhave = (cn < nfull);
        if (nhave)
            stage_ops(tq8, qe8, tt8, te8, smem + (cur ^ 1) * BUFB,
                      cn * CHUNK, wid, lane);
        // counted wait: leave next's k DMAs in flight, current buffer done
        if (nhave) {
            if (wid < 2) { asm volatile("s_waitcnt vmcnt(4)" ::: "memory"); }
            else         { asm volatile("s_waitcnt vmcnt(3)" ::: "memory"); }
        } else {
            asm volatile("s_waitcnt vmcnt(0)" ::: "memory");
        }
        __builtin_amdgcn_sched_barrier(0);
        __builtin_amdgcn_s_barrier();    // all waves' current-buffer DMAs landed

        const unsigned char* bp = smem + cur * BUFB;
        const float4* tqL = (const float4*)(bp);
        const float4* qeL = (const float4*)(bp + 4096);
        const float*  ttL = (const float*) (bp + 8192);
        const float*  teL = (const float*) (bp + 11264);
        sample_loss(tqL[t], qeL[t],
                    ttL[3*t], ttL[3*t+1], ttL[3*t+2],
                    teL[3*t], teL[3*t+1], teL[3*t+2], sr, st);

        __builtin_amdgcn_s_barrier();    // all reads done before re-staging buf
        cur ^= 1;
        c = cn;
        have = nhave;
    }

    // remainder samples (b % CHUNK) — not hit at b = 2^21, kept for safety
    for (long long s = nfull * CHUNK + (long long)blockIdx.x * blockDim.x + t;
         s < (long long)b; s += (long long)gridDim.x * blockDim.x) {
        sample_loss(tq[s], qe[s],
                    tt[3*s], tt[3*s+1], tt[3*s+2],
                    te[3*s], te[3*s+1], te[3*s+2], sr, st);
    }

    // wave (64-lane) reduction, one atomic pair per wave
    #pragma unroll
    for (int off = 32; off > 0; off >>= 1) {
        sr += __shfl_down(sr, off);
        st += __shfl_down(st, off);
    }
    if (lane == 0) {
        int slot = (blockIdx.x * 4 + wid) & (NSLOT - 1);
        double* sp = (double*)((unsigned char*)acc + (size_t)slot * 128);
        atomicAdd(&sp[0], (double)sr);
        atomicAdd(&sp[1], (double)st);
    }
}

__global__ __launch_bounds__(256) void euler_loss_finalize(
        const double* __restrict__ acc, float* __restrict__ out, int b) {
    int t = threadIdx.x;                 // 256 threads, one slot each
    const double* sp = (const double*)((const unsigned char*)acc + (size_t)t * 128);
    double sr = sp[0], st = sp[1];
    #pragma unroll
    for (int off = 32; off > 0; off >>= 1) {
        sr += __shfl_down(sr, off);
        st += __shfl_down(st, off);
    }
    __shared__ double s_r[4], s_t[4];
    int lane = t & 63, wid = t >> 6;
    if (lane == 0) { s_r[wid] = sr; s_t[wid] = st; }
    __syncthreads();
    if (t == 0) {
        double tr  = s_r[0] + s_r[1] + s_r[2] + s_r[3];
        double tts = s_t[0] + s_t[1] + s_t[2] + s_t[3];
        double inv_b = 1.0 / (double)b;
        double lr = tr * inv_b;
        double lt = tts * inv_b;
        out[0] = (float)(lr + lt);
        out[1] = (float)lt;
        out[2] = (float)lr;
    }
}

extern "C" void kernel_launch(void* const* d_in, const int* in_sizes, int n_in,
                              void* d_out, int out_size, void* d_ws, size_t ws_size,
                              hipStream_t stream) {
    // input order: point_clouds(0, unused), target_transl(1), target_rot(2),
    //              transl_err(3), rot_err(4)
    const float*  tt = (const float*)d_in[1];
    const float4* tq = (const float4*)d_in[2];
    const float*  te = (const float*)d_in[3];
    const float4* qe = (const float4*)d_in[4];
    float* out = (float*)d_out;
    int b = in_sizes[1] / 3;             // 2097152

    double* acc = (double*)d_ws;
    hipMemsetAsync(acc, 0, (size_t)NSLOT * 128, stream);   // 32 KB of slots

    long long nfull = (long long)b / CHUNK;   // 8192 chunks
    int grid = 1280;                          // 5 blocks/CU x 256 CU
    if ((long long)grid > nfull) grid = (int)nfull;
    if (grid < 1) grid = 1;
    euler_loss_kernel<<<grid, 256, 0, stream>>>(tt, tq, te, qe, acc, b);
    euler_loss_finalize<<<1, 256, 0, stream>>>(acc, out, b);
}